// Round 2
// baseline (527.714 us; speedup 1.0000x reference)
//
#include <hip/hip_runtime.h>

// 2-layer GCN: out = GCN2(relu(GCN1(x)))
// GCN(h) = dinv ⊙ (A^T + I-ish) (h W * dinv) + b   with dinv = rsqrt(deg+1)
//
// Pipeline:
//  1. deg count (atomic) -> dinv = rsqrt(deg+1)          [deg buffer reused]
//  2. p' = (x @ W1) * dinv[row]        (64x64 LDS-tiled f32 GEMM)
//  3. agg[dst] += p'[src]              (wave-per-edge, 64-lane vector atomic add)
//  4. fused: h = relu(dinv*(agg+p')+b1); q' = (h . W2)*dinv   (wave-per-node)
//  5. aggq[dst] += q'[src]             (thread-per-edge scalar atomic)
//  6. out = dinv*(aggq+q') + b2

__global__ void k_deg(const int* __restrict__ dst, int E, float* __restrict__ deg) {
    int i = blockIdx.x * blockDim.x + threadIdx.x;
    int stride = gridDim.x * blockDim.x;
    for (; i < E; i += stride) atomicAdd(&deg[dst[i]], 1.0f);
}

__global__ void k_dinv(float* __restrict__ deg, int N) {
    int i = blockIdx.x * blockDim.x + threadIdx.x;
    if (i < N) deg[i] = rsqrtf(deg[i] + 1.0f);   // +1 = self-loop
}

// p'[r][c] = (sum_k x[r][k] * W1[k][c]) * dinv[r]
__global__ __launch_bounds__(256) void k_gemm1(
    const float* __restrict__ x, const float* __restrict__ W1,
    const float* __restrict__ dinv, float* __restrict__ pp, int N)
{
    __shared__ float xs[64][132];   // +4 pad: breaks 128-float stride bank aliasing
    __shared__ float ws[128][64];
    int tid = threadIdx.x;
    int row0 = blockIdx.x * 64;
    {   // load W1 (8192 f32 = 2048 float4), coalesced
        const float4* w4 = (const float4*)W1;
        float4* s4 = (float4*)&ws[0][0];
        #pragma unroll
        for (int i = 0; i < 8; i++) s4[tid + 256 * i] = w4[tid + 256 * i];
    }
    {   // load up to 64 rows of x
        int maxr = N - row0; if (maxr > 64) maxr = 64;
        const float4* x4 = (const float4*)(x + (size_t)row0 * 128);
        int n4 = maxr * 32;
        for (int i = tid; i < n4; i += 256) {
            int r = i >> 5, c = i & 31;
            *(float4*)&xs[r][c * 4] = x4[i];
        }
    }
    __syncthreads();
    int c0 = (tid & 15) * 4;   // 16 col-groups of 4
    int r0 = (tid >> 4) * 4;   // 16 row-groups of 4
    float acc[4][4] = {};
    for (int k = 0; k < 128; k += 4) {
        float xv[4][4], wv[4][4];
        #pragma unroll
        for (int i = 0; i < 4; i++) *(float4*)xv[i] = *(const float4*)&xs[r0 + i][k];
        #pragma unroll
        for (int t = 0; t < 4; t++) *(float4*)wv[t] = *(const float4*)&ws[k + t][c0];
        #pragma unroll
        for (int i = 0; i < 4; i++)
            #pragma unroll
            for (int j = 0; j < 4; j++)
                acc[i][j] += xv[i][0] * wv[0][j] + xv[i][1] * wv[1][j]
                           + xv[i][2] * wv[2][j] + xv[i][3] * wv[3][j];
    }
    #pragma unroll
    for (int i = 0; i < 4; i++) {
        int r = row0 + r0 + i;
        if (r < N) {
            float d = dinv[r];
            float4 v = make_float4(acc[i][0] * d, acc[i][1] * d,
                                   acc[i][2] * d, acc[i][3] * d);
            *(float4*)&pp[(size_t)r * 64 + c0] = v;
        }
    }
}

// wave per edge: agg[dst][lane] += pp[src][lane]
__global__ void k_scatter1(const int* __restrict__ src, const int* __restrict__ dst,
                           int E, const float* __restrict__ pp, float* __restrict__ agg) {
    int t = blockIdx.x * blockDim.x + threadIdx.x;
    int lane = t & 63;
    int e = t >> 6;
    int estride = (gridDim.x * blockDim.x) >> 6;
    for (; e < E; e += estride) {
        int s = src[e], d = dst[e];
        atomicAdd(&agg[(size_t)d * 64 + lane], pp[(size_t)s * 64 + lane]);
    }
}

// wave per node: h = relu(dinv*(agg+pp)+b1); q' = (h . W2) * dinv
__global__ void k_fin1(const float* __restrict__ agg, const float* __restrict__ pp,
                       const float* __restrict__ dinv, const float* __restrict__ b1,
                       const float* __restrict__ W2, float* __restrict__ qp, int N) {
    int t = blockIdx.x * blockDim.x + threadIdx.x;
    int lane = t & 63;
    int node = t >> 6;
    int nstride = (gridDim.x * blockDim.x) >> 6;
    float w2 = W2[lane];
    float b = b1[lane];
    for (; node < N; node += nstride) {
        float di = dinv[node];
        size_t off = (size_t)node * 64 + lane;
        float h = di * (agg[off] + pp[off]) + b;
        h = fmaxf(h, 0.0f);
        float v = h * w2;
        #pragma unroll
        for (int m = 32; m > 0; m >>= 1) v += __shfl_xor(v, m, 64);
        if (lane == 0) qp[node] = v * di;
    }
}

__global__ void k_scatter2(const int* __restrict__ src, const int* __restrict__ dst,
                           int E, const float* __restrict__ qp, float* __restrict__ aggq) {
    int i = blockIdx.x * blockDim.x + threadIdx.x;
    int stride = gridDim.x * blockDim.x;
    for (; i < E; i += stride) atomicAdd(&aggq[dst[i]], qp[src[i]]);
}

__global__ void k_fin2(const float* __restrict__ aggq, const float* __restrict__ qp,
                       const float* __restrict__ dinv, const float* __restrict__ b2,
                       float* __restrict__ out, int N) {
    int i = blockIdx.x * blockDim.x + threadIdx.x;
    if (i < N) out[i] = dinv[i] * (aggq[i] + qp[i]) + b2[0];
}

extern "C" void kernel_launch(void* const* d_in, const int* in_sizes, int n_in,
                              void* d_out, int out_size, void* d_ws, size_t ws_size,
                              hipStream_t stream) {
    const float* x  = (const float*)d_in[0];
    const int*   ei = (const int*)d_in[1];
    const float* W1 = (const float*)d_in[2];
    const float* b1 = (const float*)d_in[3];
    const float* W2 = (const float*)d_in[4];
    const float* b2 = (const float*)d_in[5];
    float* out = (float*)d_out;

    int N = in_sizes[0] / 128;
    int E = in_sizes[1] / 2;
    const int* src = ei;
    const int* dst = ei + E;

    size_t Np = ((size_t)N + 255) & ~(size_t)255;
    float* wsf  = (float*)d_ws;
    float* deg  = wsf;                 // N floats; becomes dinv after k_dinv
    float* pp   = deg + Np;            // N*64
    float* agg  = pp + Np * 64;        // N*64
    float* qp   = agg + Np * 64;       // N
    float* aggq = qp + Np;             // N

    hipMemsetAsync(deg, 0, (size_t)N * sizeof(float), stream);
    hipMemsetAsync(agg, 0, (size_t)N * 64 * sizeof(float), stream);
    hipMemsetAsync(aggq, 0, (size_t)N * sizeof(float), stream);

    k_deg<<<1024, 256, 0, stream>>>(dst, E, deg);
    k_dinv<<<(N + 255) / 256, 256, 0, stream>>>(deg, N);
    k_gemm1<<<(N + 63) / 64, 256, 0, stream>>>(x, W1, deg, pp, N);
    k_scatter1<<<2048, 256, 0, stream>>>(src, dst, E, pp, agg);
    k_fin1<<<2048, 256, 0, stream>>>(agg, pp, deg, b1, W2, qp, N);
    k_scatter2<<<1024, 256, 0, stream>>>(src, dst, E, qp, aggq);
    k_fin2<<<(N + 255) / 256, 256, 0, stream>>>(aggq, qp, deg, b2, out, N);
}

// Round 3
// 344.655 us; speedup vs baseline: 1.5311x; 1.5311x over previous
//
#include <hip/hip_runtime.h>

// 2-layer GCN via on-device CSR (no f32 atomics).
// Pipeline:
//  1. k_deg      : int deg[dst]++                      (1.2M scalar int atomics)
//  2. k_blocksum : per-256-block sums of deg
//  3. k_scanblk  : single-block exclusive scan of block sums (nb<=512)
//  4. k_scan3    : per-block exclusive scan -> offs[], cursor[], dinv[]
//  5. k_fill     : csr[atomic cursor[dst]++] = src
//  6. k_gemm1    : pp = (x@W1)*dinv[row]               (64x64 LDS tile)
//  7. k_fused1   : wave/node: acc=pp[self]+sum pp[csr]; h=relu(dinv*acc+b1);
//                  qp = (h.W2)*dinv                     (no agg materialized)
//  8. k_fused2   : thread/node: out = dinv*(qp[self]+sum qp[csr]) + b2

__global__ void k_deg(const int* __restrict__ dst, int E, int* __restrict__ deg) {
    int i = blockIdx.x * blockDim.x + threadIdx.x;
    if (i < E) atomicAdd(&deg[dst[i]], 1);
}

__global__ void k_blocksum(const int* __restrict__ deg, int N, int* __restrict__ bsum) {
    __shared__ int s[256];
    int t = threadIdx.x;
    int i = blockIdx.x * 256 + t;
    s[t] = (i < N) ? deg[i] : 0;
    __syncthreads();
    for (int off = 128; off > 0; off >>= 1) {
        if (t < off) s[t] += s[t + off];
        __syncthreads();
    }
    if (t == 0) bsum[blockIdx.x] = s[0];
}

// single block, 512 threads; valid for nb <= 512 (N <= 131072)
__global__ void k_scanblk(int* __restrict__ bsum, int nb) {
    __shared__ int s[512];
    int t = threadIdx.x;
    int v = (t < nb) ? bsum[t] : 0;
    s[t] = v;
    __syncthreads();
    for (int off = 1; off < 512; off <<= 1) {
        int u = (t >= off) ? s[t - off] : 0;
        __syncthreads();
        s[t] += u;
        __syncthreads();
    }
    if (t < nb) bsum[t] = s[t] - v;   // exclusive
}

__global__ void k_scan3(const int* __restrict__ deg, const int* __restrict__ bsum,
                        int N, int E, int* __restrict__ offs, int* __restrict__ cursor,
                        float* __restrict__ dinv) {
    __shared__ int s[256];
    int t = threadIdx.x;
    int i = blockIdx.x * 256 + t;
    int v = (i < N) ? deg[i] : 0;
    s[t] = v;
    __syncthreads();
    for (int off = 1; off < 256; off <<= 1) {
        int u = (t >= off) ? s[t - off] : 0;
        __syncthreads();
        s[t] += u;
        __syncthreads();
    }
    if (i < N) {
        int excl = bsum[blockIdx.x] + s[t] - v;
        offs[i] = excl;
        cursor[i] = excl;
        dinv[i] = rsqrtf((float)v + 1.0f);
        if (i == N - 1) offs[N] = E;
    }
}

__global__ void k_fill(const int* __restrict__ src, const int* __restrict__ dst,
                       int E, int* __restrict__ cursor, int* __restrict__ csr) {
    int i = blockIdx.x * blockDim.x + threadIdx.x;
    if (i < E) {
        int pos = atomicAdd(&cursor[dst[i]], 1);
        csr[pos] = src[i];
    }
}

// pp[r][c] = (sum_k x[r][k] * W1[k][c]) * dinv[r]
__global__ __launch_bounds__(256) void k_gemm1(
    const float* __restrict__ x, const float* __restrict__ W1,
    const float* __restrict__ dinv, float* __restrict__ pp, int N)
{
    __shared__ float xs[64][132];
    __shared__ float ws[128][64];
    int tid = threadIdx.x;
    int row0 = blockIdx.x * 64;
    {
        const float4* w4 = (const float4*)W1;
        float4* s4 = (float4*)&ws[0][0];
        #pragma unroll
        for (int i = 0; i < 8; i++) s4[tid + 256 * i] = w4[tid + 256 * i];
    }
    {
        int maxr = N - row0; if (maxr > 64) maxr = 64;
        const float4* x4 = (const float4*)(x + (size_t)row0 * 128);
        int n4 = maxr * 32;
        for (int i = tid; i < n4; i += 256) {
            int r = i >> 5, c = i & 31;
            *(float4*)&xs[r][c * 4] = x4[i];
        }
    }
    __syncthreads();
    int c0 = (tid & 15) * 4;
    int r0 = (tid >> 4) * 4;
    float acc[4][4] = {};
    for (int k = 0; k < 128; k += 4) {
        float xv[4][4], wv[4][4];
        #pragma unroll
        for (int i = 0; i < 4; i++) *(float4*)xv[i] = *(const float4*)&xs[r0 + i][k];
        #pragma unroll
        for (int t = 0; t < 4; t++) *(float4*)wv[t] = *(const float4*)&ws[k + t][c0];
        #pragma unroll
        for (int i = 0; i < 4; i++)
            #pragma unroll
            for (int j = 0; j < 4; j++)
                acc[i][j] += xv[i][0] * wv[0][j] + xv[i][1] * wv[1][j]
                           + xv[i][2] * wv[2][j] + xv[i][3] * wv[3][j];
    }
    #pragma unroll
    for (int i = 0; i < 4; i++) {
        int r = row0 + r0 + i;
        if (r < N) {
            float d = dinv[r];
            float4 v = make_float4(acc[i][0] * d, acc[i][1] * d,
                                   acc[i][2] * d, acc[i][3] * d);
            *(float4*)&pp[(size_t)r * 64 + c0] = v;
        }
    }
}

// wave per node: acc = pp[self] + sum_{j} pp[csr[j]]; h=relu(dinv*acc+b1);
// qp = (h.W2)*dinv
__global__ void k_fused1(const int* __restrict__ offs, const int* __restrict__ csr,
                         const float* __restrict__ pp, const float* __restrict__ dinv,
                         const float* __restrict__ b1, const float* __restrict__ W2,
                         float* __restrict__ qp, int N) {
    int t = blockIdx.x * blockDim.x + threadIdx.x;
    int lane = t & 63;
    int node = t >> 6;
    int nstride = (gridDim.x * blockDim.x) >> 6;
    float w2 = W2[lane];
    float b = b1[lane];
    for (; node < N; node += nstride) {
        int start = offs[node], end = offs[node + 1];
        float acc = pp[(size_t)node * 64 + lane];   // self-loop term
        for (int j0 = start; j0 < end; j0 += 64) {
            int idx = (j0 + lane < end) ? csr[j0 + lane] : 0;
            int cnt = end - j0; if (cnt > 64) cnt = 64;
            for (int k = 0; k < cnt; k++) {
                int s = __shfl(idx, k, 64);
                acc += pp[(size_t)s * 64 + lane];
            }
        }
        float di = dinv[node];
        float h = fmaxf(di * acc + b, 0.0f);
        float v = h * w2;
        #pragma unroll
        for (int m = 32; m > 0; m >>= 1) v += __shfl_xor(v, m, 64);
        if (lane == 0) qp[node] = v * di;
    }
}

__global__ void k_fused2(const int* __restrict__ offs, const int* __restrict__ csr,
                         const float* __restrict__ qp, const float* __restrict__ dinv,
                         const float* __restrict__ b2, float* __restrict__ out, int N) {
    int i = blockIdx.x * blockDim.x + threadIdx.x;
    if (i < N) {
        int start = offs[i], end = offs[i + 1];
        float s = qp[i];
        for (int j = start; j < end; j++) s += qp[csr[j]];
        out[i] = dinv[i] * s + b2[0];
    }
}

extern "C" void kernel_launch(void* const* d_in, const int* in_sizes, int n_in,
                              void* d_out, int out_size, void* d_ws, size_t ws_size,
                              hipStream_t stream) {
    const float* x  = (const float*)d_in[0];
    const int*   ei = (const int*)d_in[1];
    const float* W1 = (const float*)d_in[2];
    const float* b1 = (const float*)d_in[3];
    const float* W2 = (const float*)d_in[4];
    const float* b2 = (const float*)d_in[5];
    float* out = (float*)d_out;

    int N = in_sizes[0] / 128;
    int E = in_sizes[1] / 2;
    const int* src = ei;
    const int* dst = ei + E;
    int nb = (N + 255) / 256;

    size_t Np = ((size_t)N + 255) & ~(size_t)255;
    size_t Ep = ((size_t)E + 255) & ~(size_t)255;
    char* w = (char*)d_ws;
    int*   deg    = (int*)w;                 w += Np * 4;
    int*   offs   = (int*)w;                 w += (Np + 256) * 4;
    int*   cursor = (int*)w;                 w += Np * 4;
    int*   bsum   = (int*)w;                 w += 2048;          // up to 512 block sums
    int*   csr    = (int*)w;                 w += Ep * 4;
    float* dinv   = (float*)w;               w += Np * 4;
    float* pp     = (float*)w;               w += Np * 64 * 4;
    float* qp     = (float*)w;               /* Np * 4 */

    hipMemsetAsync(deg, 0, (size_t)N * sizeof(int), stream);

    k_deg<<<(E + 255) / 256, 256, 0, stream>>>(dst, E, deg);
    k_blocksum<<<nb, 256, 0, stream>>>(deg, N, bsum);
    k_scanblk<<<1, 512, 0, stream>>>(bsum, nb);
    k_scan3<<<nb, 256, 0, stream>>>(deg, bsum, N, E, offs, cursor, dinv);
    k_fill<<<(E + 255) / 256, 256, 0, stream>>>(src, dst, E, cursor, csr);
    k_gemm1<<<(N + 63) / 64, 256, 0, stream>>>(x, W1, dinv, pp, N);
    k_fused1<<<2048, 256, 0, stream>>>(offs, csr, pp, dinv, b1, W2, qp, N);
    k_fused2<<<(N + 255) / 256, 256, 0, stream>>>(offs, csr, qp, dinv, b2, out, N);
}

// Round 4
// 226.465 us; speedup vs baseline: 2.3302x; 1.5219x over previous
//
#include <hip/hip_runtime.h>

// 2-layer GCN. CSR built via LDS multisplit (no global atomics), pp stored bf16.
// Pipeline:
//  A k_hist     : per-block LDS hist over NB dst-buckets (bucket = dst>>8)
//  B k_bscan    : per-bucket exclusive scan over the 256 blocks
//  C k_cscan    : exclusive scan of bucket totals -> bucket bases
//  D k_dscatter : scatter packed (src<<8|dst&255) into bucket-grouped array (LDS cursors)
//  E k_bfill    : per-bucket node hist+scan -> offs/dinv; csr via LDS staging (coalesced)
//  F k_gemm1    : pp = (x@W1)*dinv[row], stored bf16 (quantize AFTER f32 compute)
//  G k_fused1   : wave/node, 2 edges/iter, half-wave 128B bf16 gathers;
//                 h=relu(dinv*acc+b1); qp=(h.W2)*dinv
//  H k_fused2   : thread/node: out = dinv*(qp[self]+sum qp[csr]) + b2

#define NBLK 256          // blocks in hist/scatter passes (fixed: k_bscan scans 256)
#define MAXB 8192         // LDS staging cap per bucket (avg ~3070 for E=1.2M)

__device__ __forceinline__ float bf2f(unsigned short u) {
    union { unsigned int i; float f; } v; v.i = ((unsigned int)u) << 16; return v.f;
}
__device__ __forceinline__ unsigned short f2bf(float f) {
    union { float f; unsigned int i; } v; v.f = f;
    unsigned int r = (v.i + 0x7fffu + ((v.i >> 16) & 1u)) >> 16;
    return (unsigned short)r;
}

// A: per-block histogram of dst buckets
__global__ __launch_bounds__(256) void k_hist(const int* __restrict__ dst, int E, int chunk,
                                              int NB, int* __restrict__ bh) {
    __shared__ int h[512];
    int blk = blockIdx.x, t = threadIdx.x;
    h[t] = 0; h[t + 256] = 0;
    __syncthreads();
    int e0 = blk * chunk, e1 = min(E, e0 + chunk);
    for (int e = e0 + t; e < e1; e += 256) atomicAdd(&h[dst[e] >> 8], 1);
    __syncthreads();
    for (int k = t; k < NB; k += 256) bh[blk * NB + k] = h[k];
}

// B: per-bucket exclusive scan over NBLK block counts; btot[k] = bucket total
__global__ __launch_bounds__(256) void k_bscan(int* __restrict__ bh, int NB,
                                               int* __restrict__ btot) {
    __shared__ int s[256];
    int k = blockIdx.x, t = threadIdx.x;
    int v = bh[t * NB + k];
    s[t] = v;
    __syncthreads();
    for (int off = 1; off < 256; off <<= 1) {
        int u = (t >= off) ? s[t - off] : 0;
        __syncthreads();
        s[t] += u;
        __syncthreads();
    }
    bh[t * NB + k] = s[t] - v;
    if (t == 255) btot[k] = s[255];
}

// C: exclusive scan of bucket totals (NB <= 512)
__global__ __launch_bounds__(512) void k_cscan(const int* __restrict__ btot, int NB, int E,
                                               int* __restrict__ bbase, int* __restrict__ offs,
                                               int N) {
    __shared__ int s[512];
    int t = threadIdx.x;
    int v = (t < NB) ? btot[t] : 0;
    s[t] = v;
    __syncthreads();
    for (int off = 1; off < 512; off <<= 1) {
        int u = (t >= off) ? s[t - off] : 0;
        __syncthreads();
        s[t] += u;
        __syncthreads();
    }
    if (t < NB) bbase[t] = s[t] - v;
    if (t == 0) offs[N] = E;
}

// D: scatter packed records into bucket-grouped order
__global__ __launch_bounds__(256) void k_dscatter(const int* __restrict__ src,
                                                  const int* __restrict__ dst, int E, int chunk,
                                                  const int* __restrict__ bh,
                                                  const int* __restrict__ bbase, int NB,
                                                  unsigned int* __restrict__ grouped) {
    __shared__ int cur[512];
    int blk = blockIdx.x, t = threadIdx.x;
    for (int k = t; k < NB; k += 256) cur[k] = bbase[k] + bh[blk * NB + k];
    __syncthreads();
    int e0 = blk * chunk, e1 = min(E, e0 + chunk);
    for (int e = e0 + t; e < e1; e += 256) {
        int d = dst[e];
        int pos = atomicAdd(&cur[d >> 8], 1);
        grouped[pos] = ((unsigned int)src[e] << 8) | (unsigned int)(d & 255);
    }
}

// E: per-bucket node hist/scan -> offs, dinv; csr fill via LDS staging
__global__ __launch_bounds__(256) void k_bfill(const unsigned int* __restrict__ grouped,
                                               const int* __restrict__ bbase,
                                               const int* __restrict__ btot, int N,
                                               int* __restrict__ offs, int* __restrict__ csr,
                                               float* __restrict__ dinv) {
    __shared__ int hist[256], pfx[256], cur[256];
    __shared__ int stage[MAXB];
    int k = blockIdx.x, t = threadIdx.x;
    int base = bbase[k], cnt = btot[k];
    hist[t] = 0;
    __syncthreads();
    for (int i = t; i < cnt; i += 256) atomicAdd(&hist[grouped[base + i] & 255u], 1);
    __syncthreads();
    int v = hist[t];
    pfx[t] = v;
    __syncthreads();
    for (int off = 1; off < 256; off <<= 1) {
        int u = (t >= off) ? pfx[t - off] : 0;
        __syncthreads();
        pfx[t] += u;
        __syncthreads();
    }
    int excl = pfx[t] - v;
    cur[t] = excl;
    int node = (k << 8) + t;
    if (node < N) {
        offs[node] = base + excl;
        dinv[node] = rsqrtf((float)v + 1.0f);
    }
    __syncthreads();
    if (cnt <= MAXB) {
        for (int i = t; i < cnt; i += 256) {
            unsigned int p = grouped[base + i];
            int pos = atomicAdd(&cur[p & 255u], 1);
            stage[pos] = (int)(p >> 8);
        }
        __syncthreads();
        for (int i = t; i < cnt; i += 256) csr[base + i] = stage[i];
    } else {  // overflow fallback (never for uniform random)
        for (int i = t; i < cnt; i += 256) {
            unsigned int p = grouped[base + i];
            int pos = atomicAdd(&cur[p & 255u], 1);
            csr[base + pos] = (int)(p >> 8);
        }
    }
}

// F: pp[r][c] = (sum_k x[r][k]*W1[k][c]) * dinv[r], f32 compute, bf16 store
__global__ __launch_bounds__(256) void k_gemm1(
    const float* __restrict__ x, const float* __restrict__ W1,
    const float* __restrict__ dinv, unsigned short* __restrict__ ppb, int N)
{
    __shared__ float xs[64][132];
    __shared__ float ws[128][64];
    int tid = threadIdx.x;
    int row0 = blockIdx.x * 64;
    {
        const float4* w4 = (const float4*)W1;
        float4* s4 = (float4*)&ws[0][0];
        #pragma unroll
        for (int i = 0; i < 8; i++) s4[tid + 256 * i] = w4[tid + 256 * i];
    }
    {
        int maxr = N - row0; if (maxr > 64) maxr = 64;
        const float4* x4 = (const float4*)(x + (size_t)row0 * 128);
        int n4 = maxr * 32;
        for (int i = tid; i < n4; i += 256) {
            int r = i >> 5, c = i & 31;
            *(float4*)&xs[r][c * 4] = x4[i];
        }
    }
    __syncthreads();
    int c0 = (tid & 15) * 4;
    int r0 = (tid >> 4) * 4;
    float acc[4][4] = {};
    for (int kk = 0; kk < 128; kk += 4) {
        float xv[4][4], wv[4][4];
        #pragma unroll
        for (int i = 0; i < 4; i++) *(float4*)xv[i] = *(const float4*)&xs[r0 + i][kk];
        #pragma unroll
        for (int t = 0; t < 4; t++) *(float4*)wv[t] = *(const float4*)&ws[kk + t][c0];
        #pragma unroll
        for (int i = 0; i < 4; i++)
            #pragma unroll
            for (int j = 0; j < 4; j++)
                acc[i][j] += xv[i][0] * wv[0][j] + xv[i][1] * wv[1][j]
                           + xv[i][2] * wv[2][j] + xv[i][3] * wv[3][j];
    }
    #pragma unroll
    for (int i = 0; i < 4; i++) {
        int r = row0 + r0 + i;
        if (r < N) {
            float d = dinv[r];
            ushort4 o;
            o.x = f2bf(acc[i][0] * d);
            o.y = f2bf(acc[i][1] * d);
            o.z = f2bf(acc[i][2] * d);
            o.w = f2bf(acc[i][3] * d);
            *(ushort4*)&ppb[(size_t)r * 64 + c0] = o;
        }
    }
}

// G: wave/node, 2 edges per iter; lane owns cols 2*hl,2*hl+1 (hl=lane&31)
__global__ void k_fused1(const int* __restrict__ offs, const int* __restrict__ csr,
                         const unsigned short* __restrict__ ppb,
                         const float* __restrict__ dinv, const float* __restrict__ b1,
                         const float* __restrict__ W2, float* __restrict__ qp, int N) {
    int t = blockIdx.x * blockDim.x + threadIdx.x;
    int lane = t & 63;
    int half = lane >> 5;
    int hl = lane & 31;
    int node = t >> 6;
    int nstride = (gridDim.x * blockDim.x) >> 6;
    float w2a = W2[2 * hl], w2b = W2[2 * hl + 1];
    float ba = b1[2 * hl], bb = b1[2 * hl + 1];
    for (; node < N; node += nstride) {
        int start = offs[node], end = offs[node + 1];
        float acca = 0.0f, accb = 0.0f;
        if (half == 0) {  // self-loop term counted once
            unsigned int v = *(const unsigned int*)&ppb[(size_t)node * 64 + 2 * hl];
            acca = bf2f((unsigned short)v);
            accb = bf2f((unsigned short)(v >> 16));
        }
        for (int j0 = start; j0 < end; j0 += 64) {
            int jj = j0 + lane;
            int idx = (jj < end) ? csr[jj] : 0;
            int cnt = end - j0; if (cnt > 64) cnt = 64;
            for (int kk = 0; kk < cnt; kk += 2) {
                int s0 = __shfl(idx, kk, 64);
                int s1 = (kk + 1 < cnt) ? __shfl(idx, kk + 1, 64) : -1;
                int s = half ? s1 : s0;
                if (s >= 0) {
                    unsigned int v = *(const unsigned int*)&ppb[(size_t)s * 64 + 2 * hl];
                    acca += bf2f((unsigned short)v);
                    accb += bf2f((unsigned short)(v >> 16));
                }
            }
        }
        acca += __shfl_xor(acca, 32, 64);
        accb += __shfl_xor(accb, 32, 64);
        float di = dinv[node];
        float ha = fmaxf(di * acca + ba, 0.0f);
        float hb = fmaxf(di * accb + bb, 0.0f);
        float v = ha * w2a + hb * w2b;
        #pragma unroll
        for (int m = 16; m > 0; m >>= 1) v += __shfl_xor(v, m, 64);
        if (lane == 0) qp[node] = v * di;
    }
}

// H: out = dinv*(qp[self] + sum qp[csr]) + b2
__global__ void k_fused2(const int* __restrict__ offs, const int* __restrict__ csr,
                         const float* __restrict__ qp, const float* __restrict__ dinv,
                         const float* __restrict__ b2, float* __restrict__ out, int N) {
    int i = blockIdx.x * blockDim.x + threadIdx.x;
    if (i < N) {
        int start = offs[i], end = offs[i + 1];
        float s = qp[i];
        for (int j = start; j < end; j++) s += qp[csr[j]];
        out[i] = dinv[i] * s + b2[0];
    }
}

extern "C" void kernel_launch(void* const* d_in, const int* in_sizes, int n_in,
                              void* d_out, int out_size, void* d_ws, size_t ws_size,
                              hipStream_t stream) {
    const float* x  = (const float*)d_in[0];
    const int*   ei = (const int*)d_in[1];
    const float* W1 = (const float*)d_in[2];
    const float* b1 = (const float*)d_in[3];
    const float* W2 = (const float*)d_in[4];
    const float* b2 = (const float*)d_in[5];
    float* out = (float*)d_out;

    int N = in_sizes[0] / 128;
    int E = in_sizes[1] / 2;
    const int* src = ei;
    const int* dst = ei + E;
    int NB = (N + 255) >> 8;          // dst buckets (<=512 for N<=131072)
    int chunk = (E + NBLK - 1) / NBLK;

    size_t Np = ((size_t)N + 255) & ~(size_t)255;
    size_t Ep = ((size_t)E + 255) & ~(size_t)255;
    char* w = (char*)d_ws;
    int* bh      = (int*)w;            w += (size_t)NBLK * 512 * 4;   // [blk][bucket]
    int* btot    = (int*)w;            w += 512 * 4;
    int* bbase   = (int*)w;            w += 512 * 4;
    unsigned int* grouped = (unsigned int*)w;  w += Ep * 4;
    int* offs    = (int*)w;            w += (Np + 256) * 4;
    int* csr     = (int*)w;            w += Ep * 4;
    float* dinv  = (float*)w;          w += Np * 4;
    unsigned short* ppb = (unsigned short*)w;  w += Np * 64 * 2;
    float* qp    = (float*)w;          /* Np*4 */

    k_hist<<<NBLK, 256, 0, stream>>>(dst, E, chunk, NB, bh);
    k_bscan<<<NB, 256, 0, stream>>>(bh, NB, btot);
    k_cscan<<<1, 512, 0, stream>>>(btot, NB, E, bbase, offs, N);
    k_dscatter<<<NBLK, 256, 0, stream>>>(src, dst, E, chunk, bh, bbase, NB, grouped);
    k_bfill<<<NB, 256, 0, stream>>>(grouped, bbase, btot, N, offs, csr, dinv);
    k_gemm1<<<(N + 63) / 64, 256, 0, stream>>>(x, W1, dinv, ppb, N);
    k_fused1<<<2048, 256, 0, stream>>>(offs, csr, ppb, dinv, b1, W2, qp, N);
    k_fused2<<<(N + 255) / 256, 256, 0, stream>>>(offs, csr, qp, dinv, b2, out, N);
}